// Round 3
// baseline (655.293 us; speedup 1.0000x reference)
//
#include <hip/hip_runtime.h>

// Problem constants
#define Dd 256           // embedding dim (== channel count C)
#define Kc 1024          // num codes
#define SPATIAL 16384    // 16*32*32
#define NROWS 65536      // 4 * SPATIAL
#define NELEM 16777216   // 4*256*16384
#define LOSS_OFF 16777216
#define IDX_OFF  16777217
#define PERP_OFF (16777217 + 65536)

// ws layout (bytes):
//   0       : double loss_sum
//   256     : int counts[1024]
//   8192    : float eT[256*1024]      (1 MB)
//   1056768 : float se[1024]          (4 KB)   ||e_j||^2 (f32, f64-accurate)
//   1060864 : float sx[65536]         (256 KB) ||x_n||^2 (f32, f64-accurate)
//   1323008 : int   idx[65536]        (256 KB)

__global__ __launch_bounds__(256) void prep_kernel(const float* __restrict__ emb,
                                                   float* __restrict__ eT,
                                                   float* __restrict__ se) {
  const int j = blockIdx.x;      // code
  const int c = threadIdx.x;     // channel
  float v = emb[j * Dd + c];
  eT[c * Kc + j] = v;
  double s = (double)v * (double)v;
  #pragma unroll
  for (int off = 32; off; off >>= 1) s += __shfl_down(s, off, 64);
  __shared__ double ws4[4];
  if ((threadIdx.x & 63) == 0) ws4[threadIdx.x >> 6] = s;
  __syncthreads();
  if (threadIdx.x == 0) se[j] = (float)(ws4[0] + ws4[1] + ws4[2] + ws4[3]);
}

// ||x_n||^2 in f64, rounded to f32. 64 rows per block; 4 thread-groups of 64
// channels each.
__global__ __launch_bounds__(256) void sx_kernel(const float* __restrict__ z,
                                                 float* __restrict__ sx) {
  __shared__ double part[4][64];
  const int tid = threadIdx.x;
  const int r  = tid & 63;        // spatial offset within 64-row group
  const int cg = tid >> 6;        // channel group 0..3
  const int blk = blockIdx.x;
  const int b  = blk >> 8;
  const int s0 = (blk & 255) << 6;
  const float* zb = z + (size_t)b * (Dd * SPATIAL);
  double acc = 0.0;
  for (int c = cg * 64; c < cg * 64 + 64; ++c) {
    const float v = zb[(size_t)c * SPATIAL + s0 + r];
    acc += (double)v * (double)v;
  }
  part[cg][r] = acc;
  __syncthreads();
  if (tid < 64) {
    sx[b * SPATIAL + s0 + tid] =
        (float)(part[0][tid] + part[1][tid] + part[2][tid] + part[3][tid]);
  }
}

// 64 rows x all 1024 codes per block; K-tiles of 64 codes, D-chunks of 32.
// Per-(row,code) dot is ONE sequential f32 FMA chain over k=0..255 ascending
// (mirrors BLAS sgemm microkernel rounding). Final score mirrors numpy:
// dist = fl(fl(sx + se_j) - fl(2*P)).
__global__ __launch_bounds__(256) void argmin_kernel(const float* __restrict__ z,
                                                     const float* __restrict__ eT,
                                                     const float* __restrict__ se,
                                                     const float* __restrict__ sx,
                                                     float* __restrict__ out_idx_f,
                                                     int* __restrict__ idx_i,
                                                     int* __restrict__ counts) {
  __shared__ float As[32 * 64];
  __shared__ float Bs[32 * 64];
  __shared__ float ses[Kc];
  __shared__ float sxs[64];
  __shared__ float redS1[64 * 16];
  __shared__ int   redI1[64 * 16];

  const int tid = threadIdx.x;
  const int tc = tid & 15;        // 16 col-threads
  const int tr = tid >> 4;        // 16 row-threads
  const int blk = blockIdx.x;
  const int b  = blk >> 8;        // batch
  const int s0 = (blk & 255) << 6;
  const float* zb = z + (size_t)b * (Dd * SPATIAL);

  #pragma unroll
  for (int i = 0; i < 4; ++i) ses[tid + 256 * i] = se[tid + 256 * i];
  if (tid < 64) sxs[tid] = sx[b * SPATIAL + s0 + tid];

  float s1[4];
  int   j1[4];
  #pragma unroll
  for (int r = 0; r < 4; ++r) { s1[r] = 3.4e38f; j1[r] = 0; }

  for (int j0 = 0; j0 < Kc; j0 += 64) {
    float acc[4][4];
    #pragma unroll
    for (int rr = 0; rr < 4; ++rr)
      #pragma unroll
      for (int cc = 0; cc < 4; ++cc) acc[rr][cc] = 0.0f;

    for (int c0 = 0; c0 < Dd; c0 += 32) {
      __syncthreads();
      #pragma unroll
      for (int i = 0; i < 8; ++i) {
        const int e  = i * 256 + tid;
        const int ci = e >> 6;
        const int r  = e & 63;
        As[e] = zb[(size_t)(c0 + ci) * SPATIAL + s0 + r];
        Bs[e] = eT[(c0 + ci) * Kc + j0 + r];
      }
      __syncthreads();
      #pragma unroll
      for (int d = 0; d < 32; ++d) {
        const float4 av = *reinterpret_cast<const float4*>(&As[d * 64 + 4 * tr]);
        const float4 bv = *reinterpret_cast<const float4*>(&Bs[d * 64 + 4 * tc]);
        const float aa[4] = {av.x, av.y, av.z, av.w};
        const float bb[4] = {bv.x, bv.y, bv.z, bv.w};
        #pragma unroll
        for (int rr = 0; rr < 4; ++rr)
          #pragma unroll
          for (int cc = 0; cc < 4; ++cc)
            acc[rr][cc] = fmaf(aa[rr], bb[cc], acc[rr][cc]);
      }
    }
    #pragma unroll
    for (int rr = 0; rr < 4; ++rr) {
      const float sxr = sxs[4 * tr + rr];
      #pragma unroll
      for (int cc = 0; cc < 4; ++cc) {
        const int j = j0 + 4 * tc + cc;
        const float t1 = sxr + ses[j];            // fl(sx + se_j)
        const float s  = t1 - 2.0f * acc[rr][cc]; // fl(t1 - 2P) (2P exact)
        if (s < s1[rr] || (s == s1[rr] && j < j1[rr])) {
          s1[rr] = s; j1[rr] = j;
        }
      }
    }
  }

  #pragma unroll
  for (int rr = 0; rr < 4; ++rr) {
    redS1[(4 * tr + rr) * 16 + tc] = s1[rr];
    redI1[(4 * tr + rr) * 16 + tc] = j1[rr];
  }
  __syncthreads();
  if (tid < 64) {
    float bs = redS1[tid * 16];
    int   bj = redI1[tid * 16];
    #pragma unroll
    for (int t = 1; t < 16; ++t) {
      const float a1 = redS1[tid * 16 + t];
      const int   aj = redI1[tid * 16 + t];
      if (a1 < bs || (a1 == bs && aj < bj)) { bs = a1; bj = aj; }
    }
    const int n = b * SPATIAL + s0 + tid;
    out_idx_f[n] = (float)bj;
    idx_i[n] = bj;
    atomicAdd(&counts[bj], 1);
  }
}

__global__ __launch_bounds__(256) void phase2_kernel(const float* __restrict__ z,
                                                     const float* __restrict__ eT,
                                                     const int* __restrict__ idx_i,
                                                     float* __restrict__ out_zq,
                                                     double* __restrict__ loss_sum) {
  __shared__ int sidx[64];
  __shared__ double dred[4];
  const int tid = threadIdx.x;
  const int blk = blockIdx.x;
  const int b  = blk >> 8;
  const int s0 = (blk & 255) << 6;
  if (tid < 64) sidx[tid] = idx_i[b * SPATIAL + s0 + tid];
  __syncthreads();
  const int s = tid & 63;
  const int coff = tid >> 6;   // 0..3
  const size_t zb = (size_t)b * (Dd * SPATIAL);
  const int myidx = sidx[s];
  double lsum = 0.0;
  for (int c = coff; c < Dd; c += 4) {
    const size_t off = zb + (size_t)c * SPATIAL + s0 + s;
    const float zv = z[off];
    const float zq = eT[c * Kc + myidx];
    out_zq[off] = zv + (zq - zv);      // straight-through (== z_q up to ulp)
    const float d = zv - zq;
    lsum += (double)d * (double)d;
  }
  #pragma unroll
  for (int off = 32; off; off >>= 1) lsum += __shfl_down(lsum, off, 64);
  if ((tid & 63) == 0) dred[tid >> 6] = lsum;
  __syncthreads();
  if (tid == 0) atomicAdd(loss_sum, dred[0] + dred[1] + dred[2] + dred[3]);
}

__global__ __launch_bounds__(256) void finalize_kernel(const int* __restrict__ counts,
                                                       const double* __restrict__ loss_sum,
                                                       float* __restrict__ out) {
  const int tid = threadIdx.x;
  double local = 0.0;
  for (int k = tid; k < Kc; k += 256) {
    const double p = (double)counts[k] / (double)NROWS;
    local += p * log(p + 1e-10);
  }
  #pragma unroll
  for (int off = 32; off; off >>= 1) local += __shfl_down(local, off, 64);
  __shared__ double dred[4];
  if ((tid & 63) == 0) dred[tid >> 6] = local;
  __syncthreads();
  if (tid == 0) {
    const double H = dred[0] + dred[1] + dred[2] + dred[3];
    out[PERP_OFF] = (float)exp(-H);
    out[LOSS_OFF] = (float)(0.25 * loss_sum[0] / (double)NELEM);
  }
}

extern "C" void kernel_launch(void* const* d_in, const int* in_sizes, int n_in,
                              void* d_out, int out_size, void* d_ws, size_t ws_size,
                              hipStream_t stream) {
  const float* z   = (const float*)d_in[0];
  const float* emb = (const float*)d_in[1];
  float* out = (float*)d_out;
  char* ws = (char*)d_ws;

  double* loss_sum = (double*)(ws + 0);
  int*    counts   = (int*)(ws + 256);
  float*  eT       = (float*)(ws + 8192);
  float*  se       = (float*)(ws + 8192 + 1048576);
  float*  sx       = (float*)(ws + 8192 + 1048576 + 4096);
  int*    idx_i    = (int*)(ws + 8192 + 1048576 + 4096 + 262144);

  hipMemsetAsync(d_ws, 0, 8192, stream);  // zero loss_sum + counts

  prep_kernel<<<Kc, 256, 0, stream>>>(emb, eT, se);
  sx_kernel<<<1024, 256, 0, stream>>>(z, sx);
  argmin_kernel<<<1024, 256, 0, stream>>>(z, eT, se, sx, out + IDX_OFF, idx_i, counts);
  phase2_kernel<<<1024, 256, 0, stream>>>(z, eT, idx_i, out, loss_sum);
  finalize_kernel<<<1, 256, 0, stream>>>(counts, loss_sum, out);
}

// Round 4
// 488.718 us; speedup vs baseline: 1.3408x; 1.3408x over previous
//
#include <hip/hip_runtime.h>

// Problem constants
#define Dd 256           // embedding dim (== channel count C)
#define Kc 1024          // num codes
#define SPATIAL 16384    // 16*32*32
#define NROWS 65536      // 4 * SPATIAL
#define NELEM 16777216   // 4*256*16384
#define LOSS_OFF 16777216
#define IDX_OFF  16777217
#define PERP_OFF (16777217 + 65536)
#define MARGIN 3.5e-4f
#define SCS 1030         // f16 score LDS row stride (odd dword => conflict-free col scans)

typedef _Float16 f16x8 __attribute__((ext_vector_type(8)));
typedef _Float16 f16x2 __attribute__((ext_vector_type(2)));
typedef float f32x4 __attribute__((ext_vector_type(4)));

// ============================ NEW FAST PATH =================================

// emb -> e_f16 (K x D row-major, scaled by 1024 to avoid f16 denormals) + se (f64->f32)
__global__ __launch_bounds__(256) void prep2_kernel(const float* __restrict__ emb,
                                                    _Float16* __restrict__ ef,
                                                    float* __restrict__ se) {
  const int j = blockIdx.x, c = threadIdx.x;
  float v = emb[j * Dd + c];
  ef[j * Dd + c] = (_Float16)(v * 1024.0f);
  double s = (double)v * (double)v;
  #pragma unroll
  for (int off = 32; off; off >>= 1) s += __shfl_down(s, off, 64);
  __shared__ double ws4[4];
  if ((threadIdx.x & 63) == 0) ws4[threadIdx.x >> 6] = s;
  __syncthreads();
  if (threadIdx.x == 0) se[j] = (float)(ws4[0] + ws4[1] + ws4[2] + ws4[3]);
}

// z (B,C,S) -> zT_f16 (N x D row-major) + sx (f64->f32, same summation order as r3)
__global__ __launch_bounds__(256) void transpose_kernel(const float* __restrict__ z,
                                                        _Float16* __restrict__ zT,
                                                        float* __restrict__ sx) {
  __shared__ _Float16 th[64 * 264];
  __shared__ double part[4][64];
  const int tid = threadIdx.x, cg = tid >> 6, r = tid & 63;
  const int blk = blockIdx.x, b = blk >> 8, s0 = (blk & 255) << 6;
  const float* zb = z + (size_t)b * (Dd * SPATIAL);
  double acc = 0.0;
  for (int c = cg * 64; c < cg * 64 + 64; ++c) {
    float v = zb[(size_t)c * SPATIAL + s0 + r];
    th[r * 264 + c] = (_Float16)v;
    acc += (double)v * (double)v;
  }
  part[cg][r] = acc;
  __syncthreads();
  if (tid < 64)
    sx[b * SPATIAL + s0 + tid] =
        (float)(part[0][tid] + part[1][tid] + part[2][tid] + part[3][tid]);
  const int rr = tid >> 2, p = tid & 3;
  uint4* dstv = (uint4*)(zT + ((size_t)(b * SPATIAL + s0 + rr)) * Dd + p * 64);
  const uint4* srcv = (const uint4*)(th + rr * 264 + p * 64);
  #pragma unroll
  for (int i = 0; i < 8; ++i) dstv[i] = srcv[i];
}

// fp16 MFMA prefilter: 64 rows x all 1024 cols per block; fast scores se-2P in
// f16 LDS; per-row min + flag all cols within MARGIN -> candidate lists.
__global__ __launch_bounds__(512) void prefilter_kernel(const _Float16* __restrict__ zT,
                                                        const _Float16* __restrict__ ef,
                                                        const float* __restrict__ se,
                                                        int* __restrict__ candcount,
                                                        int* __restrict__ cand_g) {
  __shared__ _Float16 sc[64 * SCS];
  __shared__ float selds[Kc];
  __shared__ int cnts[64];
  __shared__ int cands[64][8];
  __shared__ float rmin[64][8];
  __shared__ float rthr[64];

  const int tid = threadIdx.x;
  const int n0 = blockIdx.x * 64;
  selds[tid] = se[tid];
  selds[tid + 512] = se[tid + 512];
  if (tid < 64) cnts[tid] = 0;

  const int w = tid >> 6, lane = tid & 63, q = lane >> 4, l15 = lane & 15;
  const int rtg = (w & 1) * 2;       // row-tile pair base (0 or 2)
  const int ctg = (w >> 1) * 2;      // col-tile pair base within j-tile (0,2,4,6)
  const _Float16* za0 = zT + ((size_t)(n0 + rtg * 16 + l15)) * Dd + q * 8;
  const _Float16* za1 = za0 + 16 * Dd;

  for (int j0 = 0; j0 < Kc; j0 += 128) {
    const int c0 = j0 + ctg * 16 + l15;
    const _Float16* eb0 = ef + (size_t)c0 * Dd + q * 8;
    const _Float16* eb1 = eb0 + 16 * Dd;
    f32x4 a00 = {0.f, 0.f, 0.f, 0.f}, a01 = a00, a10 = a00, a11 = a00;
    #pragma unroll
    for (int kk = 0; kk < 8; ++kk) {
      f16x8 A0 = *(const f16x8*)(za0 + kk * 32);
      f16x8 A1 = *(const f16x8*)(za1 + kk * 32);
      f16x8 B0 = *(const f16x8*)(eb0 + kk * 32);
      f16x8 B1 = *(const f16x8*)(eb1 + kk * 32);
      a00 = __builtin_amdgcn_mfma_f32_16x16x32_f16(A0, B0, a00, 0, 0, 0);
      a01 = __builtin_amdgcn_mfma_f32_16x16x32_f16(A0, B1, a01, 0, 0, 0);
      a10 = __builtin_amdgcn_mfma_f32_16x16x32_f16(A1, B0, a10, 0, 0, 0);
      a11 = __builtin_amdgcn_mfma_f32_16x16x32_f16(A1, B1, a11, 0, 0, 0);
    }
    const float se0 = selds[c0], se1 = selds[c0 + 16];
    #pragma unroll
    for (int reg = 0; reg < 4; ++reg) {
      const int r0 = rtg * 16 + q * 4 + reg, r1 = r0 + 16;
      sc[r0 * SCS + c0]      = (_Float16)fmaf(-0.001953125f, a00[reg], se0);
      sc[r0 * SCS + c0 + 16] = (_Float16)fmaf(-0.001953125f, a01[reg], se1);
      sc[r1 * SCS + c0]      = (_Float16)fmaf(-0.001953125f, a10[reg], se0);
      sc[r1 * SCS + c0 + 16] = (_Float16)fmaf(-0.001953125f, a11[reg], se1);
    }
  }
  __syncthreads();

  // scan: r = lane (row), seg = wave; each scans 128 cols
  const int r = tid & 63, seg = tid >> 6;
  const _Float16* base = sc + r * SCS + seg * 128;
  float mn = 3.4e38f;
  for (int i = 0; i < 64; ++i) {
    f16x2 h = *(const f16x2*)(base + i * 2);
    mn = fminf(mn, fminf((float)h[0], (float)h[1]));
  }
  rmin[r][seg] = mn;
  __syncthreads();
  if (tid < 64) {
    float m2 = rmin[tid][0];
    #pragma unroll
    for (int t = 1; t < 8; ++t) m2 = fminf(m2, rmin[tid][t]);
    rthr[tid] = m2 + MARGIN;
  }
  __syncthreads();
  const float thr = rthr[r];
  for (int i = 0; i < 64; ++i) {
    f16x2 h = *(const f16x2*)(base + i * 2);
    #pragma unroll
    for (int u = 0; u < 2; ++u) {
      if ((float)h[u] < thr) {
        int pos = atomicAdd(&cnts[r], 1);
        if (pos < 8) cands[r][pos] = seg * 128 + i * 2 + u;
      }
    }
  }
  __syncthreads();
  if (tid < 64) candcount[n0 + tid] = min(cnts[tid], 8);
  cand_g[(size_t)(n0 + (tid & 63)) * 8 + (tid >> 6)] = cands[tid & 63][tid >> 6];
}

// cnt==1 rows resolved directly; others appended to hard list
__global__ __launch_bounds__(256) void resolve_easy_kernel(const int* __restrict__ candcount,
                                                           const int* __restrict__ cand_g,
                                                           float* __restrict__ out_idx_f,
                                                           int* __restrict__ idx_i,
                                                           int* __restrict__ counts,
                                                           int* __restrict__ hardcnt,
                                                           int* __restrict__ hardlist) {
  const int n = blockIdx.x * 256 + threadIdx.x;
  const int cnt = candcount[n];
  if (cnt == 1) {
    const int j = cand_g[(size_t)n * 8];
    idx_i[n] = j;
    out_idx_f[n] = (float)j;
    atomicAdd(&counts[j], 1);
  } else {
    const int pos = atomicAdd(hardcnt, 1);
    hardlist[pos] = n;
  }
}

// exact reference-rounded rescore of hard rows (<=8 candidates, one per lane)
__global__ __launch_bounds__(256) void resolve_hard_kernel(const float* __restrict__ z,
                                                           const float* __restrict__ emb,
                                                           const float* __restrict__ se,
                                                           const float* __restrict__ sx,
                                                           const int* __restrict__ candcount,
                                                           const int* __restrict__ cand_g,
                                                           const int* __restrict__ hardcnt,
                                                           const int* __restrict__ hardlist,
                                                           float* __restrict__ out_idx_f,
                                                           int* __restrict__ idx_i,
                                                           int* __restrict__ counts) {
  __shared__ float xs[4][256];
  const int tid = threadIdx.x, w = tid >> 6, lane = tid & 63;
  const int hc = *hardcnt;
  const int nw = gridDim.x * 4;
  for (int i = blockIdx.x * 4 + w; i < hc; i += nw) {
    const int n = hardlist[i];
    const int b = n >> 14, s = n & 16383;
    #pragma unroll
    for (int ro = 0; ro < 4; ++ro)
      xs[w][ro * 64 + lane] =
          z[(size_t)b * (Dd * SPATIAL) + (size_t)(ro * 64 + lane) * SPATIAL + s];
    asm volatile("s_waitcnt lgkmcnt(0) vmcnt(0)" ::: "memory");
    const int cnt = min(candcount[n], 8);
    float scb = 3.4e38f;
    int jb = 0x7fffffff;
    if (lane < cnt) {
      jb = cand_g[(size_t)n * 8 + lane];
      const float4* ep = (const float4*)(emb + (size_t)jb * Dd);
      float acc = 0.f;
      #pragma unroll 8
      for (int kk = 0; kk < 64; ++kk) {
        const float4 e4 = ep[kk];
        const float* xp = &xs[w][kk * 4];
        acc = fmaf(xp[0], e4.x, acc);
        acc = fmaf(xp[1], e4.y, acc);
        acc = fmaf(xp[2], e4.z, acc);
        acc = fmaf(xp[3], e4.w, acc);
      }
      const float t1 = sx[n] + se[jb];   // fl(sx + se_j)
      scb = t1 - 2.0f * acc;             // fl(t1 - 2P), 2P exact
    }
    #pragma unroll
    for (int l = 1; l < 8; ++l) {
      const float so = __shfl(scb, l, 64);
      const int jo = __shfl(jb, l, 64);
      if (lane == 0) {
        if (so < scb || (so == scb && jo < jb)) { scb = so; jb = jo; }
      }
    }
    if (lane == 0) {
      idx_i[n] = jb;
      out_idx_f[n] = (float)jb;
      atomicAdd(&counts[jb], 1);
    }
  }
}

// gather z_q via LDS-staged e-rows + straight-through write + f64 loss
__global__ __launch_bounds__(256) void phase2b_kernel(const float* __restrict__ z,
                                                      const float* __restrict__ emb,
                                                      const int* __restrict__ idx_i,
                                                      float* __restrict__ out_zq,
                                                      double* __restrict__ loss_sum) {
  __shared__ float els[64 * 257];
  __shared__ int sidx[64];
  __shared__ double dred[4];
  const int tid = threadIdx.x;
  const int blk = blockIdx.x, b = blk >> 8, s0 = (blk & 255) << 6;
  if (tid < 64) sidx[tid] = idx_i[b * SPATIAL + s0 + tid];
  __syncthreads();
  {
    const int rr = tid >> 2, p = tid & 3;
    const float* ep = emb + (size_t)sidx[rr] * Dd + p * 64;
    float* dl = els + rr * 257 + p * 64;
    #pragma unroll
    for (int i = 0; i < 64; i += 4) {
      const float4 e4 = *(const float4*)(ep + i);
      dl[i] = e4.x; dl[i + 1] = e4.y; dl[i + 2] = e4.z; dl[i + 3] = e4.w;
    }
  }
  __syncthreads();
  const int s = tid & 63, coff = tid >> 6;
  const size_t zb = (size_t)b * (Dd * SPATIAL);
  double lsum = 0.0;
  for (int c = coff; c < Dd; c += 4) {
    const size_t off = zb + (size_t)c * SPATIAL + s0 + s;
    const float zv = z[off];
    const float zq = els[s * 257 + c];
    out_zq[off] = zv + (zq - zv);
    const float d = zv - zq;
    lsum += (double)d * (double)d;
  }
  #pragma unroll
  for (int off = 32; off; off >>= 1) lsum += __shfl_down(lsum, off, 64);
  if ((tid & 63) == 0) dred[tid >> 6] = lsum;
  __syncthreads();
  if (tid == 0) atomicAdd(loss_sum, dred[0] + dred[1] + dred[2] + dred[3]);
}

__global__ __launch_bounds__(256) void finalize_kernel(const int* __restrict__ counts,
                                                       const double* __restrict__ loss_sum,
                                                       float* __restrict__ out) {
  const int tid = threadIdx.x;
  double local = 0.0;
  for (int k = tid; k < Kc; k += 256) {
    const double p = (double)counts[k] / (double)NROWS;
    local += p * log(p + 1e-10);
  }
  #pragma unroll
  for (int off = 32; off; off >>= 1) local += __shfl_down(local, off, 64);
  __shared__ double dred[4];
  if ((tid & 63) == 0) dred[tid >> 6] = local;
  __syncthreads();
  if (tid == 0) {
    const double H = dred[0] + dred[1] + dred[2] + dred[3];
    out[PERP_OFF] = (float)exp(-H);
    out[LOSS_OFF] = (float)(0.25 * loss_sum[0] / (double)NELEM);
  }
}

// ===================== OLD (round-3) FALLBACK PATH ==========================

__global__ __launch_bounds__(256) void prep_kernel(const float* __restrict__ emb,
                                                   float* __restrict__ eT,
                                                   float* __restrict__ se) {
  const int j = blockIdx.x, c = threadIdx.x;
  float v = emb[j * Dd + c];
  eT[c * Kc + j] = v;
  double s = (double)v * (double)v;
  #pragma unroll
  for (int off = 32; off; off >>= 1) s += __shfl_down(s, off, 64);
  __shared__ double ws4[4];
  if ((threadIdx.x & 63) == 0) ws4[threadIdx.x >> 6] = s;
  __syncthreads();
  if (threadIdx.x == 0) se[j] = (float)(ws4[0] + ws4[1] + ws4[2] + ws4[3]);
}

__global__ __launch_bounds__(256) void sx_kernel(const float* __restrict__ z,
                                                 float* __restrict__ sx) {
  __shared__ double part[4][64];
  const int tid = threadIdx.x, r = tid & 63, cg = tid >> 6;
  const int blk = blockIdx.x, b = blk >> 8, s0 = (blk & 255) << 6;
  const float* zb = z + (size_t)b * (Dd * SPATIAL);
  double acc = 0.0;
  for (int c = cg * 64; c < cg * 64 + 64; ++c) {
    const float v = zb[(size_t)c * SPATIAL + s0 + r];
    acc += (double)v * (double)v;
  }
  part[cg][r] = acc;
  __syncthreads();
  if (tid < 64)
    sx[b * SPATIAL + s0 + tid] =
        (float)(part[0][tid] + part[1][tid] + part[2][tid] + part[3][tid]);
}

__global__ __launch_bounds__(256) void argmin_kernel(const float* __restrict__ z,
                                                     const float* __restrict__ eT,
                                                     const float* __restrict__ se,
                                                     const float* __restrict__ sx,
                                                     float* __restrict__ out_idx_f,
                                                     int* __restrict__ idx_i,
                                                     int* __restrict__ counts) {
  __shared__ float As[32 * 64];
  __shared__ float Bs[32 * 64];
  __shared__ float ses[Kc];
  __shared__ float sxs[64];
  __shared__ float redS1[64 * 16];
  __shared__ int   redI1[64 * 16];
  const int tid = threadIdx.x, tc = tid & 15, tr = tid >> 4;
  const int blk = blockIdx.x, b = blk >> 8, s0 = (blk & 255) << 6;
  const float* zb = z + (size_t)b * (Dd * SPATIAL);
  #pragma unroll
  for (int i = 0; i < 4; ++i) ses[tid + 256 * i] = se[tid + 256 * i];
  if (tid < 64) sxs[tid] = sx[b * SPATIAL + s0 + tid];
  float s1[4]; int j1[4];
  #pragma unroll
  for (int r = 0; r < 4; ++r) { s1[r] = 3.4e38f; j1[r] = 0; }
  for (int j0 = 0; j0 < Kc; j0 += 64) {
    float acc[4][4];
    #pragma unroll
    for (int rr = 0; rr < 4; ++rr)
      #pragma unroll
      for (int cc = 0; cc < 4; ++cc) acc[rr][cc] = 0.0f;
    for (int c0 = 0; c0 < Dd; c0 += 32) {
      __syncthreads();
      #pragma unroll
      for (int i = 0; i < 8; ++i) {
        const int e = i * 256 + tid, ci = e >> 6, r = e & 63;
        As[e] = zb[(size_t)(c0 + ci) * SPATIAL + s0 + r];
        Bs[e] = eT[(c0 + ci) * Kc + j0 + r];
      }
      __syncthreads();
      #pragma unroll
      for (int d = 0; d < 32; ++d) {
        const float4 av = *reinterpret_cast<const float4*>(&As[d * 64 + 4 * tr]);
        const float4 bv = *reinterpret_cast<const float4*>(&Bs[d * 64 + 4 * tc]);
        const float aa[4] = {av.x, av.y, av.z, av.w};
        const float bb[4] = {bv.x, bv.y, bv.z, bv.w};
        #pragma unroll
        for (int rr = 0; rr < 4; ++rr)
          #pragma unroll
          for (int cc = 0; cc < 4; ++cc)
            acc[rr][cc] = fmaf(aa[rr], bb[cc], acc[rr][cc]);
      }
    }
    #pragma unroll
    for (int rr = 0; rr < 4; ++rr) {
      const float sxr = sxs[4 * tr + rr];
      #pragma unroll
      for (int cc = 0; cc < 4; ++cc) {
        const int j = j0 + 4 * tc + cc;
        const float t1 = sxr + ses[j];
        const float s = t1 - 2.0f * acc[rr][cc];
        if (s < s1[rr] || (s == s1[rr] && j < j1[rr])) { s1[rr] = s; j1[rr] = j; }
      }
    }
  }
  #pragma unroll
  for (int rr = 0; rr < 4; ++rr) {
    redS1[(4 * tr + rr) * 16 + tc] = s1[rr];
    redI1[(4 * tr + rr) * 16 + tc] = j1[rr];
  }
  __syncthreads();
  if (tid < 64) {
    float bs = redS1[tid * 16];
    int bj = redI1[tid * 16];
    #pragma unroll
    for (int t = 1; t < 16; ++t) {
      const float a1 = redS1[tid * 16 + t];
      const int aj = redI1[tid * 16 + t];
      if (a1 < bs || (a1 == bs && aj < bj)) { bs = a1; bj = aj; }
    }
    const int n = b * SPATIAL + s0 + tid;
    out_idx_f[n] = (float)bj;
    idx_i[n] = bj;
    atomicAdd(&counts[bj], 1);
  }
}

__global__ __launch_bounds__(256) void phase2_kernel(const float* __restrict__ z,
                                                     const float* __restrict__ eT,
                                                     const int* __restrict__ idx_i,
                                                     float* __restrict__ out_zq,
                                                     double* __restrict__ loss_sum) {
  __shared__ int sidx[64];
  __shared__ double dred[4];
  const int tid = threadIdx.x;
  const int blk = blockIdx.x, b = blk >> 8, s0 = (blk & 255) << 6;
  if (tid < 64) sidx[tid] = idx_i[b * SPATIAL + s0 + tid];
  __syncthreads();
  const int s = tid & 63, coff = tid >> 6;
  const size_t zb = (size_t)b * (Dd * SPATIAL);
  const int myidx = sidx[s];
  double lsum = 0.0;
  for (int c = coff; c < Dd; c += 4) {
    const size_t off = zb + (size_t)c * SPATIAL + s0 + s;
    const float zv = z[off];
    const float zq = eT[c * Kc + myidx];
    out_zq[off] = zv + (zq - zv);
    const float d = zv - zq;
    lsum += (double)d * (double)d;
  }
  #pragma unroll
  for (int off = 32; off; off >>= 1) lsum += __shfl_down(lsum, off, 64);
  if ((tid & 63) == 0) dred[tid >> 6] = lsum;
  __syncthreads();
  if (tid == 0) atomicAdd(loss_sum, dred[0] + dred[1] + dred[2] + dred[3]);
}

// ================================ LAUNCH ====================================

extern "C" void kernel_launch(void* const* d_in, const int* in_sizes, int n_in,
                              void* d_out, int out_size, void* d_ws, size_t ws_size,
                              hipStream_t stream) {
  const float* z   = (const float*)d_in[0];
  const float* emb = (const float*)d_in[1];
  float* out = (float*)d_out;
  char* ws = (char*)d_ws;

  // fast-path ws layout
  const size_t OFF_SE   = 8192;
  const size_t OFF_SX   = 12288;
  const size_t OFF_EF   = 274432;
  const size_t OFF_ZT   = 798720;
  const size_t OFF_IDX  = 34353152;
  const size_t OFF_CCT  = 34615296;
  const size_t OFF_CAND = 34877440;
  const size_t OFF_HARD = 36974592;
  const size_t NEED     = 37236736;

  double* loss_sum = (double*)(ws + 0);
  int*    hardcnt  = (int*)(ws + 8);
  int*    counts   = (int*)(ws + 256);

  hipMemsetAsync(d_ws, 0, 8192, stream);  // loss_sum + hardcnt + counts

  if (ws_size >= NEED) {
    float*     se        = (float*)(ws + OFF_SE);
    float*     sx        = (float*)(ws + OFF_SX);
    _Float16*  ef        = (_Float16*)(ws + OFF_EF);
    _Float16*  zT        = (_Float16*)(ws + OFF_ZT);
    int*       idx_i     = (int*)(ws + OFF_IDX);
    int*       candcount = (int*)(ws + OFF_CCT);
    int*       cand_g    = (int*)(ws + OFF_CAND);
    int*       hardlist  = (int*)(ws + OFF_HARD);

    prep2_kernel<<<Kc, 256, 0, stream>>>(emb, ef, se);
    transpose_kernel<<<1024, 256, 0, stream>>>(z, zT, sx);
    prefilter_kernel<<<1024, 512, 0, stream>>>(zT, ef, se, candcount, cand_g);
    resolve_easy_kernel<<<256, 256, 0, stream>>>(candcount, cand_g, out + IDX_OFF,
                                                 idx_i, counts, hardcnt, hardlist);
    resolve_hard_kernel<<<256, 256, 0, stream>>>(z, emb, se, sx, candcount, cand_g,
                                                 hardcnt, hardlist, out + IDX_OFF,
                                                 idx_i, counts);
    phase2b_kernel<<<1024, 256, 0, stream>>>(z, emb, idx_i, out, loss_sum);
    finalize_kernel<<<1, 256, 0, stream>>>(counts, loss_sum, out);
  } else {
    // round-3 proven fallback
    float* eT    = (float*)(ws + 8192);
    float* se    = (float*)(ws + 8192 + 1048576);
    float* sx    = (float*)(ws + 8192 + 1048576 + 4096);
    int*   idx_i = (int*)(ws + 8192 + 1048576 + 4096 + 262144);

    prep_kernel<<<Kc, 256, 0, stream>>>(emb, eT, se);
    sx_kernel<<<1024, 256, 0, stream>>>(z, sx);
    argmin_kernel<<<1024, 256, 0, stream>>>(z, eT, se, sx, out + IDX_OFF, idx_i, counts);
    phase2_kernel<<<1024, 256, 0, stream>>>(z, eT, idx_i, out, loss_sum);
    finalize_kernel<<<1, 256, 0, stream>>>(counts, loss_sum, out);
  }
}

// Round 5
// 325.573 us; speedup vs baseline: 2.0127x; 1.5011x over previous
//
#include <hip/hip_runtime.h>

// Problem constants
#define Dd 256           // embedding dim (== channel count C)
#define Kc 1024          // num codes
#define SPATIAL 16384    // 16*32*32
#define NROWS 65536      // 4 * SPATIAL
#define NELEM 16777216   // 4*256*16384
#define LOSS_OFF 16777216
#define IDX_OFF  16777217
#define PERP_OFF (16777217 + 65536)
#define MARGIN 3.5e-4f

typedef _Float16 f16x8 __attribute__((ext_vector_type(8)));
typedef _Float16 f16x2 __attribute__((ext_vector_type(2)));
typedef float f32x4 __attribute__((ext_vector_type(4)));

// ============================ FAST PATH =====================================

// emb -> ef (K x D row-major f16, scaled by 1024) + se (f64->f32)
__global__ __launch_bounds__(256) void prep2_kernel(const float* __restrict__ emb,
                                                    _Float16* __restrict__ ef,
                                                    float* __restrict__ se) {
  const int j = blockIdx.x, c = threadIdx.x;
  float v = emb[j * Dd + c];
  ef[j * Dd + c] = (_Float16)(v * 1024.0f);
  double s = (double)v * (double)v;
  #pragma unroll
  for (int off = 32; off; off >>= 1) s += __shfl_down(s, off, 64);
  __shared__ double ws4[4];
  if ((threadIdx.x & 63) == 0) ws4[threadIdx.x >> 6] = s;
  __syncthreads();
  if (threadIdx.x == 0) se[j] = (float)(ws4[0] + ws4[1] + ws4[2] + ws4[3]);
}

// Fused: z-tile transpose->f16 (LDS) + sx (f64) + MFMA scores in registers +
// per-row min + margin flagging. 32 rows x 1024 cols per block; wave w owns
// cols [w*256, w*256+256). Scores packed f16x2 in 64 VGPRs (no big LDS).
__global__ __launch_bounds__(256, 2) void prefilter2_kernel(const float* __restrict__ z,
                                                            const _Float16* __restrict__ ef,
                                                            const float* __restrict__ se,
                                                            float* __restrict__ sx,
                                                            float* __restrict__ rowmin,
                                                            int* __restrict__ candcount,
                                                            int* __restrict__ cand_g) {
  __shared__ _Float16 As[32 * 272];    // 17408 B transposed z tile
  __shared__ double sxp[8][32];
  __shared__ float selds[Kc];
  __shared__ int cnts[32];
  __shared__ int cands[32][8];
  __shared__ float rminw[4][32];
  __shared__ float rthr[32];

  const int tid = threadIdx.x;
  const int n0 = blockIdx.x * 32;
  const int b = n0 >> 14, s0 = n0 & 16383;
  const float* zb = z + (size_t)b * (Dd * SPATIAL) + s0;

  // stage + transpose + sx partials
  {
    const int r = tid & 31, cp = tid >> 5;
    double acc = 0.0;
    #pragma unroll 8
    for (int c = cp * 32; c < cp * 32 + 32; ++c) {
      const float v = zb[(size_t)c * SPATIAL + r];
      As[r * 272 + c] = (_Float16)v;
      acc += (double)v * (double)v;
    }
    sxp[cp][r] = acc;
  }
  #pragma unroll
  for (int i = 0; i < 4; ++i) selds[tid + 256 * i] = se[tid + 256 * i];
  if (tid < 32) cnts[tid] = 0;
  __syncthreads();
  if (tid < 32) {
    double s = 0.0;
    #pragma unroll
    for (int p = 0; p < 8; ++p) s += sxp[p][tid];
    sx[n0 + tid] = (float)s;
  }

  const int w = tid >> 6, lane = tid & 63, q = lane >> 4, l15 = lane & 15;
  const int colbase = w * 256;

  // A fragments -> registers (rows rt*16+l15, k = kk*32 + q*8)
  f16x8 Afrag[2][8];
  #pragma unroll
  for (int rt = 0; rt < 2; ++rt)
    #pragma unroll
    for (int kk = 0; kk < 8; ++kk)
      Afrag[rt][kk] = *(const f16x8*)(&As[(rt * 16 + l15) * 272 + kk * 32 + q * 8]);

  const _Float16* efb = ef + (size_t)(colbase + l15) * Dd + q * 8;

  float rmin8[8];
  #pragma unroll
  for (int i = 0; i < 8; ++i) rmin8[i] = 3.4e38f;
  f16x2 scst[16][4];

  #pragma unroll
  for (int ct = 0; ct < 16; ++ct) {
    const _Float16* bp = efb + (size_t)ct * 16 * Dd;
    f16x8 B[8];
    #pragma unroll
    for (int kk = 0; kk < 8; ++kk) B[kk] = *(const f16x8*)(bp + kk * 32);
    f32x4 a0 = {0.f, 0.f, 0.f, 0.f}, a1 = {0.f, 0.f, 0.f, 0.f};
    #pragma unroll
    for (int kk = 0; kk < 8; ++kk) {
      a0 = __builtin_amdgcn_mfma_f32_16x16x32_f16(Afrag[0][kk], B[kk], a0, 0, 0, 0);
      a1 = __builtin_amdgcn_mfma_f32_16x16x32_f16(Afrag[1][kk], B[kk], a1, 0, 0, 0);
    }
    const float sec = selds[colbase + ct * 16 + l15];
    #pragma unroll
    for (int reg = 0; reg < 4; ++reg) {
      const float sc0 = fmaf(-0.001953125f, a0[reg], sec);  // se - 2P (/1024 scale)
      const float sc1 = fmaf(-0.001953125f, a1[reg], sec);
      rmin8[reg]     = fminf(rmin8[reg], sc0);
      rmin8[reg + 4] = fminf(rmin8[reg + 4], sc1);
      scst[ct][reg] = (f16x2){(_Float16)sc0, (_Float16)sc1};
    }
  }

  // cross-lane row-min (lanes sharing q hold same rows)
  #pragma unroll
  for (int m = 1; m <= 8; m <<= 1)
    #pragma unroll
    for (int i = 0; i < 8; ++i) rmin8[i] = fminf(rmin8[i], __shfl_xor(rmin8[i], m, 64));
  if (l15 == 0) {
    #pragma unroll
    for (int reg = 0; reg < 4; ++reg) {
      rminw[w][q * 4 + reg] = rmin8[reg];
      rminw[w][16 + q * 4 + reg] = rmin8[4 + reg];
    }
  }
  __syncthreads();
  if (tid < 32) {
    const float m = fminf(fminf(rminw[0][tid], rminw[1][tid]),
                          fminf(rminw[2][tid], rminw[3][tid]));
    rowmin[n0 + tid] = m;
    rthr[tid] = m + MARGIN;
  }
  __syncthreads();

  // flag pass over register scores
  float thr0[4], thr1[4];
  #pragma unroll
  for (int reg = 0; reg < 4; ++reg) {
    thr0[reg] = rthr[q * 4 + reg];
    thr1[reg] = rthr[16 + q * 4 + reg];
  }
  #pragma unroll
  for (int ct = 0; ct < 16; ++ct) {
    const int col = colbase + ct * 16 + l15;
    #pragma unroll
    for (int reg = 0; reg < 4; ++reg) {
      if ((float)scst[ct][reg][0] < thr0[reg]) {
        const int pos = atomicAdd(&cnts[q * 4 + reg], 1);
        if (pos < 8) cands[q * 4 + reg][pos] = col;
      }
      if ((float)scst[ct][reg][1] < thr1[reg]) {
        const int pos = atomicAdd(&cnts[16 + q * 4 + reg], 1);
        if (pos < 8) cands[16 + q * 4 + reg][pos] = col;
      }
    }
  }
  __syncthreads();
  if (tid < 32) candcount[n0 + tid] = cnts[tid];   // >8 => full-rescore marker
  cand_g[(size_t)(n0 + (tid >> 3)) * 8 + (tid & 7)] = cands[tid >> 3][tid & 7];
}

// cnt==1 rows resolved directly (+loss partial); others appended to hard list
__global__ __launch_bounds__(256) void resolve_easy_kernel(const int* __restrict__ candcount,
                                                           const int* __restrict__ cand_g,
                                                           const float* __restrict__ sx,
                                                           const float* __restrict__ rowmin,
                                                           float* __restrict__ out_idx_f,
                                                           int* __restrict__ idx_i,
                                                           int* __restrict__ counts,
                                                           int* __restrict__ hardcnt,
                                                           int* __restrict__ hardlist,
                                                           double* __restrict__ loss_sum) {
  const int tid = threadIdx.x;
  const int n = blockIdx.x * 256 + tid;
  const int cnt = candcount[n];
  double lp = 0.0;
  if (cnt == 1) {
    const int j = cand_g[(size_t)n * 8];
    idx_i[n] = j;
    out_idx_f[n] = (float)j;
    atomicAdd(&counts[j], 1);
    lp = (double)sx[n] + (double)rowmin[n];   // ||z-e||^2 = sx + (se - 2P)
  } else {
    const int pos = atomicAdd(hardcnt, 1);
    hardlist[pos] = n;
  }
  #pragma unroll
  for (int off = 32; off; off >>= 1) lp += __shfl_down(lp, off, 64);
  __shared__ double dred[4];
  if ((tid & 63) == 0) dred[tid >> 6] = lp;
  __syncthreads();
  if (tid == 0) atomicAdd(loss_sum, dred[0] + dred[1] + dred[2] + dred[3]);
}

// exact reference-rounded rescore of hard rows; cnt<=8 lane-parallel cands,
// cnt>8 full 1024-code scan. Also accumulates loss for these rows.
__global__ __launch_bounds__(256) void resolve_hard_kernel(const float* __restrict__ z,
                                                           const float* __restrict__ emb,
                                                           const float* __restrict__ se,
                                                           const float* __restrict__ sx,
                                                           const int* __restrict__ candcount,
                                                           const int* __restrict__ cand_g,
                                                           const int* __restrict__ hardcnt,
                                                           const int* __restrict__ hardlist,
                                                           float* __restrict__ out_idx_f,
                                                           int* __restrict__ idx_i,
                                                           int* __restrict__ counts,
                                                           double* __restrict__ loss_sum) {
  __shared__ float xs[4][256];
  const int tid = threadIdx.x, w = tid >> 6, lane = tid & 63;
  const int hc = *hardcnt;
  const int nw = gridDim.x * 4;
  double wloss = 0.0;
  for (int i = blockIdx.x * 4 + w; i < hc; i += nw) {
    const int n = hardlist[i];
    const int b = n >> 14, s = n & 16383;
    #pragma unroll
    for (int ro = 0; ro < 4; ++ro)
      xs[w][ro * 64 + lane] =
          z[(size_t)b * (Dd * SPATIAL) + (size_t)(ro * 64 + lane) * SPATIAL + s];
    asm volatile("s_waitcnt lgkmcnt(0) vmcnt(0)" ::: "memory");
    const int cnt = candcount[n];
    const float sxn = sx[n];
    float scb = 3.4e38f;
    int jb = 0x7fffffff;
    if (cnt <= 8) {
      if (lane < cnt) {
        jb = cand_g[(size_t)n * 8 + lane];
        const float4* ep = (const float4*)(emb + (size_t)jb * Dd);
        float acc = 0.f;
        #pragma unroll 8
        for (int kk = 0; kk < 64; ++kk) {
          const float4 e4 = ep[kk];
          const float* xp = &xs[w][kk * 4];
          acc = fmaf(xp[0], e4.x, acc);
          acc = fmaf(xp[1], e4.y, acc);
          acc = fmaf(xp[2], e4.z, acc);
          acc = fmaf(xp[3], e4.w, acc);
        }
        const float t1 = sxn + se[jb];
        scb = t1 - 2.0f * acc;
      }
    } else {
      // full exact scan: 16 codes per lane, ascending j per lane
      for (int jj = 0; jj < 16; ++jj) {
        const int j = lane * 16 + jj;
        const float4* ep = (const float4*)(emb + (size_t)j * Dd);
        float acc = 0.f;
        #pragma unroll 8
        for (int kk = 0; kk < 64; ++kk) {
          const float4 e4 = ep[kk];
          const float* xp = &xs[w][kk * 4];
          acc = fmaf(xp[0], e4.x, acc);
          acc = fmaf(xp[1], e4.y, acc);
          acc = fmaf(xp[2], e4.z, acc);
          acc = fmaf(xp[3], e4.w, acc);
        }
        const float t1 = sxn + se[j];
        const float sc = t1 - 2.0f * acc;
        if (sc < scb) { scb = sc; jb = j; }   // ascending j => strict < keeps first
      }
    }
    #pragma unroll
    for (int m = 1; m <= 32; m <<= 1) {
      const float so = __shfl_xor(scb, m, 64);
      const int jo = __shfl_xor(jb, m, 64);
      if (so < scb || (so == scb && jo < jb)) { scb = so; jb = jo; }
    }
    if (lane == 0) {
      idx_i[n] = jb;
      out_idx_f[n] = (float)jb;
      atomicAdd(&counts[jb], 1);
      wloss += (double)sxn + (double)scb;
    }
  }
  if (lane == 0) atomicAdd(loss_sum, wloss);
}

// gather-only z_q write (out == z_q; straight-through is identity in fwd)
__global__ __launch_bounds__(256) void phase2c_kernel(const float* __restrict__ emb,
                                                      const int* __restrict__ idx_i,
                                                      float* __restrict__ out_zq) {
  __shared__ float els[64 * 257];
  __shared__ int sidx[64];
  const int tid = threadIdx.x;
  const int blk = blockIdx.x, b = blk >> 8, s0 = (blk & 255) << 6;
  if (tid < 64) sidx[tid] = idx_i[b * SPATIAL + s0 + tid];
  __syncthreads();
  {
    const int rr = tid >> 2, p = tid & 3;
    const float* ep = emb + (size_t)sidx[rr] * Dd + p * 64;
    float* dl = els + rr * 257 + p * 64;
    #pragma unroll
    for (int i = 0; i < 64; i += 4) {
      const float4 e4 = *(const float4*)(ep + i);
      dl[i] = e4.x; dl[i + 1] = e4.y; dl[i + 2] = e4.z; dl[i + 3] = e4.w;
    }
  }
  __syncthreads();
  const int s = tid & 63, coff = tid >> 6;
  const size_t zb = (size_t)b * (Dd * SPATIAL);
  #pragma unroll 4
  for (int c = coff; c < Dd; c += 4)
    out_zq[zb + (size_t)c * SPATIAL + s0 + s] = els[s * 257 + c];
}

__global__ __launch_bounds__(256) void finalize_kernel(const int* __restrict__ counts,
                                                       const double* __restrict__ loss_sum,
                                                       float* __restrict__ out) {
  const int tid = threadIdx.x;
  double local = 0.0;
  for (int k = tid; k < Kc; k += 256) {
    const double p = (double)counts[k] / (double)NROWS;
    local += p * log(p + 1e-10);
  }
  #pragma unroll
  for (int off = 32; off; off >>= 1) local += __shfl_down(local, off, 64);
  __shared__ double dred[4];
  if ((tid & 63) == 0) dred[tid >> 6] = local;
  __syncthreads();
  if (tid == 0) {
    const double H = dred[0] + dred[1] + dred[2] + dred[3];
    out[PERP_OFF] = (float)exp(-H);
    out[LOSS_OFF] = (float)(0.25 * loss_sum[0] / (double)NELEM);
  }
}

// ===================== OLD (round-3) FALLBACK PATH ==========================

__global__ __launch_bounds__(256) void prep_kernel(const float* __restrict__ emb,
                                                   float* __restrict__ eT,
                                                   float* __restrict__ se) {
  const int j = blockIdx.x, c = threadIdx.x;
  float v = emb[j * Dd + c];
  eT[c * Kc + j] = v;
  double s = (double)v * (double)v;
  #pragma unroll
  for (int off = 32; off; off >>= 1) s += __shfl_down(s, off, 64);
  __shared__ double ws4[4];
  if ((threadIdx.x & 63) == 0) ws4[threadIdx.x >> 6] = s;
  __syncthreads();
  if (threadIdx.x == 0) se[j] = (float)(ws4[0] + ws4[1] + ws4[2] + ws4[3]);
}

__global__ __launch_bounds__(256) void sx_kernel(const float* __restrict__ z,
                                                 float* __restrict__ sx) {
  __shared__ double part[4][64];
  const int tid = threadIdx.x, r = tid & 63, cg = tid >> 6;
  const int blk = blockIdx.x, b = blk >> 8, s0 = (blk & 255) << 6;
  const float* zb = z + (size_t)b * (Dd * SPATIAL);
  double acc = 0.0;
  for (int c = cg * 64; c < cg * 64 + 64; ++c) {
    const float v = zb[(size_t)c * SPATIAL + s0 + r];
    acc += (double)v * (double)v;
  }
  part[cg][r] = acc;
  __syncthreads();
  if (tid < 64)
    sx[b * SPATIAL + s0 + tid] =
        (float)(part[0][tid] + part[1][tid] + part[2][tid] + part[3][tid]);
}

__global__ __launch_bounds__(256) void argmin_kernel(const float* __restrict__ z,
                                                     const float* __restrict__ eT,
                                                     const float* __restrict__ se,
                                                     const float* __restrict__ sx,
                                                     float* __restrict__ out_idx_f,
                                                     int* __restrict__ idx_i,
                                                     int* __restrict__ counts) {
  __shared__ float As[32 * 64];
  __shared__ float Bs[32 * 64];
  __shared__ float ses[Kc];
  __shared__ float sxs[64];
  __shared__ float redS1[64 * 16];
  __shared__ int   redI1[64 * 16];
  const int tid = threadIdx.x, tc = tid & 15, tr = tid >> 4;
  const int blk = blockIdx.x, b = blk >> 8, s0 = (blk & 255) << 6;
  const float* zb = z + (size_t)b * (Dd * SPATIAL);
  #pragma unroll
  for (int i = 0; i < 4; ++i) ses[tid + 256 * i] = se[tid + 256 * i];
  if (tid < 64) sxs[tid] = sx[b * SPATIAL + s0 + tid];
  float s1[4]; int j1[4];
  #pragma unroll
  for (int r = 0; r < 4; ++r) { s1[r] = 3.4e38f; j1[r] = 0; }
  for (int j0 = 0; j0 < Kc; j0 += 64) {
    float acc[4][4];
    #pragma unroll
    for (int rr = 0; rr < 4; ++rr)
      #pragma unroll
      for (int cc = 0; cc < 4; ++cc) acc[rr][cc] = 0.0f;
    for (int c0 = 0; c0 < Dd; c0 += 32) {
      __syncthreads();
      #pragma unroll
      for (int i = 0; i < 8; ++i) {
        const int e = i * 256 + tid, ci = e >> 6, r = e & 63;
        As[e] = zb[(size_t)(c0 + ci) * SPATIAL + s0 + r];
        Bs[e] = eT[(c0 + ci) * Kc + j0 + r];
      }
      __syncthreads();
      #pragma unroll
      for (int d = 0; d < 32; ++d) {
        const float4 av = *reinterpret_cast<const float4*>(&As[d * 64 + 4 * tr]);
        const float4 bv = *reinterpret_cast<const float4*>(&Bs[d * 64 + 4 * tc]);
        const float aa[4] = {av.x, av.y, av.z, av.w};
        const float bb[4] = {bv.x, bv.y, bv.z, bv.w};
        #pragma unroll
        for (int rr = 0; rr < 4; ++rr)
          #pragma unroll
          for (int cc = 0; cc < 4; ++cc)
            acc[rr][cc] = fmaf(aa[rr], bb[cc], acc[rr][cc]);
      }
    }
    #pragma unroll
    for (int rr = 0; rr < 4; ++rr) {
      const float sxr = sxs[4 * tr + rr];
      #pragma unroll
      for (int cc = 0; cc < 4; ++cc) {
        const int j = j0 + 4 * tc + cc;
        const float t1 = sxr + ses[j];
        const float s = t1 - 2.0f * acc[rr][cc];
        if (s < s1[rr] || (s == s1[rr] && j < j1[rr])) { s1[rr] = s; j1[rr] = j; }
      }
    }
  }
  #pragma unroll
  for (int rr = 0; rr < 4; ++rr) {
    redS1[(4 * tr + rr) * 16 + tc] = s1[rr];
    redI1[(4 * tr + rr) * 16 + tc] = j1[rr];
  }
  __syncthreads();
  if (tid < 64) {
    float bs = redS1[tid * 16];
    int bj = redI1[tid * 16];
    #pragma unroll
    for (int t = 1; t < 16; ++t) {
      const float a1 = redS1[tid * 16 + t];
      const int aj = redI1[tid * 16 + t];
      if (a1 < bs || (a1 == bs && aj < bj)) { bs = a1; bj = aj; }
    }
    const int n = b * SPATIAL + s0 + tid;
    out_idx_f[n] = (float)bj;
    idx_i[n] = bj;
    atomicAdd(&counts[bj], 1);
  }
}

__global__ __launch_bounds__(256) void phase2_kernel(const float* __restrict__ z,
                                                     const float* __restrict__ eT,
                                                     const int* __restrict__ idx_i,
                                                     float* __restrict__ out_zq,
                                                     double* __restrict__ loss_sum) {
  __shared__ int sidx[64];
  __shared__ double dred[4];
  const int tid = threadIdx.x;
  const int blk = blockIdx.x, b = blk >> 8, s0 = (blk & 255) << 6;
  if (tid < 64) sidx[tid] = idx_i[b * SPATIAL + s0 + tid];
  __syncthreads();
  const int s = tid & 63, coff = tid >> 6;
  const size_t zb = (size_t)b * (Dd * SPATIAL);
  const int myidx = sidx[s];
  double lsum = 0.0;
  for (int c = coff; c < Dd; c += 4) {
    const size_t off = zb + (size_t)c * SPATIAL + s0 + s;
    const float zv = z[off];
    const float zq = eT[c * Kc + myidx];
    out_zq[off] = zv + (zq - zv);
    const float d = zv - zq;
    lsum += (double)d * (double)d;
  }
  #pragma unroll
  for (int off = 32; off; off >>= 1) lsum += __shfl_down(lsum, off, 64);
  if ((tid & 63) == 0) dred[tid >> 6] = lsum;
  __syncthreads();
  if (tid == 0) atomicAdd(loss_sum, dred[0] + dred[1] + dred[2] + dred[3]);
}

// ================================ LAUNCH ====================================

extern "C" void kernel_launch(void* const* d_in, const int* in_sizes, int n_in,
                              void* d_out, int out_size, void* d_ws, size_t ws_size,
                              hipStream_t stream) {
  const float* z   = (const float*)d_in[0];
  const float* emb = (const float*)d_in[1];
  float* out = (float*)d_out;
  char* ws = (char*)d_ws;

  // fast-path ws layout
  const size_t OFF_SE   = 8192;
  const size_t OFF_SX   = 12288;
  const size_t OFF_EF   = 274432;
  const size_t OFF_RM   = 798720;
  const size_t OFF_IDX  = 1060864;
  const size_t OFF_CCT  = 1323008;
  const size_t OFF_CAND = 1585152;
  const size_t OFF_HARD = 3682304;
  const size_t NEED     = 3944448;

  double* loss_sum = (double*)(ws + 0);
  int*    hardcnt  = (int*)(ws + 8);
  int*    counts   = (int*)(ws + 256);

  hipMemsetAsync(d_ws, 0, 8192, stream);  // loss_sum + hardcnt + counts

  if (ws_size >= NEED) {
    float*    se        = (float*)(ws + OFF_SE);
    float*    sx        = (float*)(ws + OFF_SX);
    _Float16* ef        = (_Float16*)(ws + OFF_EF);
    float*    rowmin    = (float*)(ws + OFF_RM);
    int*      idx_i     = (int*)(ws + OFF_IDX);
    int*      candcount = (int*)(ws + OFF_CCT);
    int*      cand_g    = (int*)(ws + OFF_CAND);
    int*      hardlist  = (int*)(ws + OFF_HARD);

    prep2_kernel<<<Kc, 256, 0, stream>>>(emb, ef, se);
    prefilter2_kernel<<<2048, 256, 0, stream>>>(z, ef, se, sx, rowmin,
                                                candcount, cand_g);
    resolve_easy_kernel<<<256, 256, 0, stream>>>(candcount, cand_g, sx, rowmin,
                                                 out + IDX_OFF, idx_i, counts,
                                                 hardcnt, hardlist, loss_sum);
    resolve_hard_kernel<<<256, 256, 0, stream>>>(z, emb, se, sx, candcount, cand_g,
                                                 hardcnt, hardlist, out + IDX_OFF,
                                                 idx_i, counts, loss_sum);
    phase2c_kernel<<<1024, 256, 0, stream>>>(emb, idx_i, out);
    finalize_kernel<<<1, 256, 0, stream>>>(counts, loss_sum, out);
  } else {
    // round-3 proven fallback
    float* eT    = (float*)(ws + 8192);
    float* se    = (float*)(ws + 8192 + 1048576);
    float* sx    = (float*)(ws + 8192 + 1048576 + 4096);
    int*   idx_i = (int*)(ws + 8192 + 1048576 + 4096 + 262144);

    prep_kernel<<<Kc, 256, 0, stream>>>(emb, eT, se);
    sx_kernel<<<1024, 256, 0, stream>>>(z, sx);
    argmin_kernel<<<1024, 256, 0, stream>>>(z, eT, se, sx, out + IDX_OFF, idx_i, counts);
    phase2_kernel<<<1024, 256, 0, stream>>>(z, eT, idx_i, out, loss_sum);
    finalize_kernel<<<1, 256, 0, stream>>>(counts, loss_sum, out);
  }
}